// Round 5
// baseline (116.757 us; speedup 1.0000x reference)
//
#include <hip/hip_runtime.h>
#include <cmath>

// MenuLoss, round 5: memory-path tuning of the table-based kernel.
//  - float4 input loads (16 B/lane), 14 pairs/thread, grid 1024 (2 blk/batch)
//  - all global loads issued up-front (deep MLP), all 14 table gathers
//    issued together (overlapped L2-hit latency), wide reduction amortization
// Algorithm unchanged from R4: 65537-node uniform-in-theta table + lerp for
// the true side (error ~5e-5/pt, absmax was 0.0), exact 223-entry integer
// table for the pred side.

constexpr int NCOEF = 447;
constexpr int NTAB  = 223;
constexpr int M     = 65536;                 // interp intervals; M+1 nodes
constexpr float H_STEP = (float)(3.14159265358979323846 / 65536.0);
constexpr float SCALE  = (float)(65536.0 / 3.14159265358979323846);
constexpr int TPB = 256;
constexpr int F4_PER_HALF = 1792;            // 3584 pairs per half-batch

__device__ float2 g_tab[M];                  // g_tab[i] = (f_i, f_{i+1}), 512 KB
__device__ float  g_pred[NTAB];              // exact table at integer ids
__device__ float4 g_part[1024];              // per-block partials (pen, ct, cp, _)

__device__ __forceinline__ float tanh4(float v) {
  // v >= 0 here. tanh(4v) = 1 - 2/(exp(8v)+1); exp(large)->inf->rcp->0->1.
  float e = __expf(8.0f * v);
  return fmaf(-2.0f, __builtin_amdgcn_rcpf(e + 1.0f), 1.0f);
}

// One thread per table node (65537 theta nodes + 223 pred-integer nodes).
__global__ __launch_bounds__(256)
void build_tables(const float* __restrict__ coeffs)
{
  int g = blockIdx.x * 256 + threadIdx.x;
  float x;
  if (g <= M) {
    x = cosf((float)g * H_STEP);             // node value x_j = cos(j*h)
  } else if (g < M + 1 + NTAB) {
    float kf = (float)(g - (M + 1));
    float m = kf / (1.0f + __expf(50.0f * (kf - 222.5f)));  // reference _mask
    x = m / 111.0f - 1.0f;                   // exact div matches reference
  } else {
    return;
  }
  float x2 = x + x;
  float Ta = 1.0f, Tb = x;
  float acc = fmaf(coeffs[1], x, coeffs[0]);
  for (int i = 2; i + 1 < NCOEF; i += 2) {   // zero-move pairwise recurrence
    Ta = fmaf(x2, Tb, -Ta); acc = fmaf(coeffs[i],     Ta, acc);
    Tb = fmaf(x2, Ta, -Tb); acc = fmaf(coeffs[i + 1], Tb, acc);
  }
  Ta = fmaf(x2, Tb, -Ta); acc = fmaf(coeffs[NCOEF - 1], Ta, acc);  // i = 446

  if (g <= M) {                              // duplicate-store -> aligned float2 lookups
    if (g < M) g_tab[g].x = acc;
    if (g > 0) g_tab[g - 1].y = acc;
  } else {
    g_pred[g - (M + 1)] = acc;
  }
}

// grid 1024: blockIdx.x = batch*2 + half; 3584 pairs (1792 float4) per block.
__global__ __launch_bounds__(TPB)
void loss_main(const float4* __restrict__ yp4, const float4* __restrict__ yt4)
{
  __shared__ float spred[NTAB];
  __shared__ float sred[12];
  const int tid = threadIdx.x;

  if (tid < NTAB) spred[tid] = g_pred[tid];
  __syncthreads();

  const int b = blockIdx.x >> 1, h = blockIdx.x & 1;
  const size_t base = (size_t)b * 3584 + (size_t)h * F4_PER_HALF;

  // issue ALL input loads up front: 14 x 16B per thread, deep MLP
  float4 p[7], t[7];
  #pragma unroll
  for (int k = 0; k < 7; ++k) {
    p[k] = yp4[base + tid + k * TPB];
    t[k] = yt4[base + tid + k * TPB];
  }

  // true side: compute all 14 gather addresses, issue all gathers together
  float fr[14], tam[14];
  float2 f2[14];
  #pragma unroll
  for (int k = 0; k < 7; ++k) {
    float xn0 = t[k].x / 111.0f - 1.0f;      // exact div matches reference
    float th0 = acosf(xn0) * SCALE;          // in [0, M]
    int i0 = (int)th0; i0 = i0 > M - 1 ? M - 1 : i0;
    fr[2 * k] = th0 - (float)i0; tam[2 * k] = t[k].y;
    f2[2 * k] = g_tab[i0];                   // aligned 8B gather (L2-resident)

    float xn1 = t[k].z / 111.0f - 1.0f;
    float th1 = acosf(xn1) * SCALE;
    int i1 = (int)th1; i1 = i1 > M - 1 ? M - 1 : i1;
    fr[2 * k + 1] = th1 - (float)i1; tam[2 * k + 1] = t[k].w;
    f2[2 * k + 1] = g_tab[i1];
  }

  float ct = 0.0f;
  #pragma unroll
  for (int k = 0; k < 14; ++k) {
    float cal = fmaf(fr[k], f2[k].y - f2[k].x, f2[k].x);
    ct = fmaf(cal, tam[k], ct);
  }

  // pred side: penalties + exact integer-table lookup
  float pen = 0.0f, cp = 0.0f;
  #pragma unroll
  for (int k = 0; k < 7; ++k) {
    float id0 = p[k].x, am0 = p[k].y, id1 = p[k].z, am1 = p[k].w;
    float a0 = tanh4(id0), b0 = tanh4(am0);
    pen += fmaf(b0, fmaf(-2.0f, a0, 1.0f), a0) + fmaxf(id0 - 222.0f, 0.0f);
    int x0 = (int)rintf(id0); x0 = x0 < 0 ? 0 : (x0 > NTAB - 1 ? NTAB - 1 : x0);
    cp = fmaf(spred[x0], am0, cp);
    float a1 = tanh4(id1), b1 = tanh4(am1);
    pen += fmaf(b1, fmaf(-2.0f, a1, 1.0f), a1) + fmaxf(id1 - 222.0f, 0.0f);
    int x1 = (int)rintf(id1); x1 = x1 < 0 ? 0 : (x1 > NTAB - 1 ? NTAB - 1 : x1);
    cp = fmaf(spred[x1], am1, cp);
  }

  #pragma unroll
  for (int o = 32; o > 0; o >>= 1) {
    pen += __shfl_down(pen, o, 64);
    ct  += __shfl_down(ct,  o, 64);
    cp  += __shfl_down(cp,  o, 64);
  }
  const int w = tid >> 6;
  if ((tid & 63) == 0) { sred[w] = pen; sred[4 + w] = ct; sred[8 + w] = cp; }
  __syncthreads();
  if (tid == 0) {
    g_part[blockIdx.x] =
        make_float4(sred[0] + sred[1] + sred[2]  + sred[3],
                    sred[4] + sred[5] + sred[6]  + sred[7],
                    sred[8] + sred[9] + sred[10] + sred[11], 0.0f);
  }
}

__global__ __launch_bounds__(512)
void finalize(float* __restrict__ out)
{
  __shared__ float sr[8];
  int t = threadIdx.x;                        // one thread per batch
  float4 u = g_part[2 * t], v = g_part[2 * t + 1];
  float pen = u.x + v.x;
  float d = ((u.y + v.y) - (u.z + v.z)) * (1.0f / 700.0f);
  float s = fmaf(d, d, pen);                  // sum(s) = sum d^2 + sum pen
  #pragma unroll
  for (int o = 32; o > 0; o >>= 1) s += __shfl_down(s, o, 64);
  if ((t & 63) == 0) sr[t >> 6] = s;
  __syncthreads();
  if (t == 0) {
    out[0] = (sr[0] + sr[1] + sr[2] + sr[3] +
              sr[4] + sr[5] + sr[6] + sr[7]) * (1.0f / 512.0f);
  }
}

extern "C" void kernel_launch(void* const* d_in, const int* in_sizes, int n_in,
                              void* d_out, int out_size, void* d_ws, size_t ws_size,
                              hipStream_t stream) {
  build_tables<<<257, 256, 0, stream>>>((const float*)d_in[2]);
  loss_main<<<1024, TPB, 0, stream>>>(
      (const float4*)d_in[0], (const float4*)d_in[1]);
  finalize<<<1, 512, 0, stream>>>((float*)d_out);
}

// Round 6
// 106.988 us; speedup vs baseline: 1.0913x; 1.0913x over previous
//
#include <hip/hip_runtime.h>
#include <cmath>

// MenuLoss, round 6: LDS-resident theta-table + quadratic interp.
// R4/R5's 512KB L2 table was continuously evicted by the 57MB input stream
// (gathers missing to L3 ~450cyc -> loss_main stuck ~30us). Move the table
// to LDS: M=8192 theta-grid (32KB) + quadratic interp. Quad error
// ~|g'''|h^3 ~ 2e-5/pt RMS (better than R4's linear-65536), LDS gathers are
// eviction-immune at ~120cyc / 69TB/s. Pred side keeps exact 223-int table.

constexpr int NCOEF = 447;
constexpr int NTAB  = 223;
constexpr int MQ    = 8192;                  // theta intervals; MQ+1 nodes
constexpr float SCALEQ = (float)(8192.0 / 3.14159265358979323846);
constexpr float HQ     = (float)(3.14159265358979323846 / 8192.0);
constexpr int TPB = 256;

__device__ float g_tabF[MQ + 1];             // f(theta_j), 32KB + 4B
__device__ float g_pred[NTAB];               // exact table at integer ids
__device__ float4 g_part[1024];              // per-block partials (pen, ct, cp, _)

__device__ __forceinline__ float tanh4(float v) {
  // v >= 0 here. tanh(4v) = 1 - 2/(exp(8v)+1); exp(large)->inf->rcp->0->1.
  float e = __expf(8.0f * v);
  return fmaf(-2.0f, __builtin_amdgcn_rcpf(e + 1.0f), 1.0f);
}

// One thread per table node (8193 theta nodes + 223 pred-integer nodes).
__global__ __launch_bounds__(256)
void build_tables(const float* __restrict__ coeffs)
{
  int g = blockIdx.x * 256 + threadIdx.x;
  float x;
  if (g <= MQ) {
    x = cosf((float)g * HQ);                 // node value x_j = cos(j*h)
  } else if (g < MQ + 1 + NTAB) {
    float kf = (float)(g - (MQ + 1));
    float m = kf / (1.0f + __expf(50.0f * (kf - 222.5f)));  // reference _mask
    x = m / 111.0f - 1.0f;                   // exact div matches reference
  } else {
    return;
  }
  float x2 = x + x;
  float Ta = 1.0f, Tb = x;
  float acc = fmaf(coeffs[1], x, coeffs[0]);
  for (int i = 2; i + 1 < NCOEF; i += 2) {   // zero-move pairwise recurrence
    Ta = fmaf(x2, Tb, -Ta); acc = fmaf(coeffs[i],     Ta, acc);
    Tb = fmaf(x2, Ta, -Tb); acc = fmaf(coeffs[i + 1], Tb, acc);
  }
  Ta = fmaf(x2, Tb, -Ta); acc = fmaf(coeffs[NCOEF - 1], Ta, acc);  // i = 446

  if (g <= MQ) g_tabF[g] = acc;
  else         g_pred[g - (MQ + 1)] = acc;
}

// grid 1024: blockIdx.x = batch*2 + half; 3584 pairs (1792 float4) per block.
__global__ __launch_bounds__(TPB)
void loss_main(const float4* __restrict__ yp4, const float4* __restrict__ yt4)
{
  __shared__ __align__(16) float sf[MQ + 1]; // 32KB theta table
  __shared__ float spred[NTAB];
  __shared__ float sred[12];
  const int tid = threadIdx.x;

  // cooperative LDS fill: 2048 float4 + 1 tail float (L2-hot lines)
  const float4* gt4 = (const float4*)g_tabF;
  #pragma unroll
  for (int k = 0; k < 8; ++k) ((float4*)sf)[tid + k * TPB] = gt4[tid + k * TPB];
  if (tid == 0) sf[MQ] = g_tabF[MQ];
  if (tid < NTAB) spred[tid] = g_pred[tid];
  __syncthreads();

  const int b = blockIdx.x >> 1, h = blockIdx.x & 1;
  const size_t base = (size_t)b * 3584 + (size_t)h * 1792;

  float pen = 0.0f, cp = 0.0f, ct = 0.0f;

  #pragma unroll
  for (int k = 0; k < 7; ++k) {
    float4 pv = yp4[base + tid + k * TPB];
    float4 tv = yt4[base + tid + k * TPB];

    // ---- pred side: penalties + exact integer-table lookup ----
    float a0 = tanh4(pv.x), b0 = tanh4(pv.y);
    pen += fmaf(b0, fmaf(-2.0f, a0, 1.0f), a0) + fmaxf(pv.x - 222.0f, 0.0f);
    int x0 = (int)rintf(pv.x); x0 = x0 < 0 ? 0 : (x0 > NTAB - 1 ? NTAB - 1 : x0);
    cp = fmaf(spred[x0], pv.y, cp);
    float a1 = tanh4(pv.z), b1 = tanh4(pv.w);
    pen += fmaf(b1, fmaf(-2.0f, a1, 1.0f), a1) + fmaxf(pv.z - 222.0f, 0.0f);
    int x1 = (int)rintf(pv.z); x1 = x1 < 0 ? 0 : (x1 > NTAB - 1 ? NTAB - 1 : x1);
    cp = fmaf(spred[x1], pv.w, cp);

    // ---- true side: quadratic interp on LDS theta table ----
    {
      float xn = tv.x / 111.0f - 1.0f;       // exact div matches reference
      float th = acosf(xn) * SCALEQ;         // in [0, MQ]
      float ir = rintf(th);
      ir = ir < 1.0f ? 1.0f : (ir > (float)(MQ - 1) ? (float)(MQ - 1) : ir);
      int i = (int)ir;
      float d = th - ir;                     // in [-0.5, 0.5]
      float fm = sf[i - 1], f0 = sf[i], fp = sf[i + 1];
      float ca = 0.5f * (fp - fm);
      float cb = fmaf(0.5f, fp + fm, -f0);   // (fp - 2 f0 + fm)/2
      float cal = fmaf(d, fmaf(d, cb, ca), f0);
      ct = fmaf(cal, tv.y, ct);
    }
    {
      float xn = tv.z / 111.0f - 1.0f;
      float th = acosf(xn) * SCALEQ;
      float ir = rintf(th);
      ir = ir < 1.0f ? 1.0f : (ir > (float)(MQ - 1) ? (float)(MQ - 1) : ir);
      int i = (int)ir;
      float d = th - ir;
      float fm = sf[i - 1], f0 = sf[i], fp = sf[i + 1];
      float ca = 0.5f * (fp - fm);
      float cb = fmaf(0.5f, fp + fm, -f0);
      float cal = fmaf(d, fmaf(d, cb, ca), f0);
      ct = fmaf(cal, tv.w, ct);
    }
  }

  #pragma unroll
  for (int o = 32; o > 0; o >>= 1) {
    pen += __shfl_down(pen, o, 64);
    ct  += __shfl_down(ct,  o, 64);
    cp  += __shfl_down(cp,  o, 64);
  }
  const int w = tid >> 6;
  if ((tid & 63) == 0) { sred[w] = pen; sred[4 + w] = ct; sred[8 + w] = cp; }
  __syncthreads();
  if (tid == 0) {
    g_part[blockIdx.x] =
        make_float4(sred[0] + sred[1] + sred[2]  + sred[3],
                    sred[4] + sred[5] + sred[6]  + sred[7],
                    sred[8] + sred[9] + sred[10] + sred[11], 0.0f);
  }
}

__global__ __launch_bounds__(512)
void finalize(float* __restrict__ out)
{
  __shared__ float sr[8];
  int t = threadIdx.x;                        // one thread per batch
  float4 u = g_part[2 * t], v = g_part[2 * t + 1];
  float pen = u.x + v.x;
  float d = ((u.y + v.y) - (u.z + v.z)) * (1.0f / 700.0f);
  float s = fmaf(d, d, pen);                  // sum(s) = sum d^2 + sum pen
  #pragma unroll
  for (int o = 32; o > 0; o >>= 1) s += __shfl_down(s, o, 64);
  if ((t & 63) == 0) sr[t >> 6] = s;
  __syncthreads();
  if (t == 0) {
    out[0] = (sr[0] + sr[1] + sr[2] + sr[3] +
              sr[4] + sr[5] + sr[6] + sr[7]) * (1.0f / 512.0f);
  }
}

extern "C" void kernel_launch(void* const* d_in, const int* in_sizes, int n_in,
                              void* d_out, int out_size, void* d_ws, size_t ws_size,
                              hipStream_t stream) {
  build_tables<<<33, 256, 0, stream>>>((const float*)d_in[2]);
  loss_main<<<1024, TPB, 0, stream>>>(
      (const float4*)d_in[0], (const float4*)d_in[1]);
  finalize<<<1, 512, 0, stream>>>((float*)d_out);
}